// Round 15
// baseline (111.984 us; speedup 1.0000x reference)
//
#include <hip/hip_runtime.h>
#include <hip/hip_bf16.h>
#include <cmath>

#define DMODEL 1024
#define NH 16
#define DH 64
#define SEQ 2048
#define BATCH 2

typedef __attribute__((ext_vector_type(8))) short bf16x8;
typedef __attribute__((ext_vector_type(4))) float f32x4;
typedef __attribute__((ext_vector_type(4))) unsigned int u32x4;
typedef __attribute__((ext_vector_type(8))) unsigned short u16x8;

typedef __attribute__((address_space(3))) unsigned int lds_u32;
typedef const __attribute__((address_space(1))) unsigned int g_u32;

__device__ __forceinline__ unsigned short f2bf(float f) {
    unsigned int u = __builtin_bit_cast(unsigned int, f);
    u += 0x7fffu + ((u >> 16) & 1u);
    return (unsigned short)(u >> 16);
}
// 2^x in one v_exp_f32
__device__ __forceinline__ float exp2_fast(float x) {
    float r;
    asm("v_exp_f32 %0, %1" : "=v"(r) : "v"(x));
    return r;
}

// ---------------------------------------------------------------------------
// fp32 -> bf16 cast of x, w_qkv, w_out in ONE kernel. 8 elems/thread.
// ---------------------------------------------------------------------------
__global__ __launch_bounds__(256)
void cast_all(const float* __restrict__ x, const float* __restrict__ wq,
              const float* __restrict__ wo, unsigned short* __restrict__ xb,
              unsigned short* __restrict__ wqb, unsigned short* __restrict__ wob)
{
    const int i = blockIdx.x * 256 + threadIdx.x;
    const float* src; unsigned short* dst; int off;
    if (i < 524288)      { src = x;  dst = xb;  off = i; }
    else if (i < 917504) { src = wq; dst = wqb; off = i - 524288; }
    else                 { src = wo; dst = wob; off = i - 917504; }
    const float4 a = *(const float4*)(src + (size_t)off * 8);
    const float4 b = *(const float4*)(src + (size_t)off * 8 + 4);
    u16x8 o;
    o[0] = f2bf(a.x); o[1] = f2bf(a.y); o[2] = f2bf(a.z); o[3] = f2bf(a.w);
    o[4] = f2bf(b.x); o[5] = f2bf(b.y); o[6] = f2bf(b.z); o[7] = f2bf(b.w);
    *(u16x8*)(dst + (size_t)off * 8) = o;
}

// ---------------------------------------------------------------------------
// bf16 MFMA GEMM, STRENGTH-REDUCED K-loop: C = A * B^T, K=1024, f32 accum.
// 2x-unrolled loop with explicit buffer phases: LDS dests are fixed pointers,
// global sources are running pointers (+BK/step), fragment ds_read offsets
// precomputed once. Per-step VALU ~60 -> ~12. Memory pattern / swizzles /
// barriers identical to round-14.
// EPI==0 (BM=128): fused-RoPE epilogue -> q,k [B][H][S][64], vt [B][H][64][S].
// EPI==1: plain fp32 write.
// ---------------------------------------------------------------------------
template<int BM, int EPI>
__global__ __launch_bounds__(256)
void gemm_bf16(const unsigned short* __restrict__ A,
               const unsigned short* __restrict__ B,
               float* __restrict__ oc, unsigned short* __restrict__ oq,
               unsigned short* __restrict__ ok, unsigned short* __restrict__ ovt,
               int M, int N)
{
    constexpr int K = 1024;
    constexpr int BK = 32;
    constexpr int NT = K / BK;           // 32
    constexpr int FM = BM / 32;
    __shared__ unsigned short As[2][BM * BK];
    __shared__ unsigned short Bs[2][128 * BK];

    const int t  = threadIdx.x;
    const int l  = t & 63;
    const int w  = t >> 6;
    const int g  = l >> 4;
    const int ln = l & 15;
    const int wr = w >> 1, wc = w & 1;
    const int m0 = blockIdx.y * BM;
    const int n0 = blockIdx.x * 128;

    // ---- staging: running global pointers (advance +BK per K-step) ----
    const int srow = t >> 2;                              // 0..63
    const int scol = ((t & 3) ^ ((t >> 3) & 3)) * 8;      // swizzled 16B slot
    const unsigned short* pa0 = A + (size_t)(m0 + srow) * K + scol;
    const unsigned short* pa1 = pa0 + (size_t)64 * K;     // BM==128 only
    const unsigned short* pb0 = B + (size_t)(n0 + srow) * K + scol;
    const unsigned short* pb1 = pb0 + (size_t)64 * K;

    // fixed LDS destinations (compile-time bases + t-offset)
    lds_u32* dA0a = (lds_u32*)&As[0][t * 8];
    lds_u32* dA1a = (lds_u32*)&As[1][t * 8];
    lds_u32* dA0b = (lds_u32*)&As[0][BM == 128 ? (256 + t) * 8 : 0];
    lds_u32* dA1b = (lds_u32*)&As[1][BM == 128 ? (256 + t) * 8 : 0];
    lds_u32* dB0a = (lds_u32*)&Bs[0][t * 8];
    lds_u32* dB1a = (lds_u32*)&Bs[1][t * 8];
    lds_u32* dB0b = (lds_u32*)&Bs[0][(256 + t) * 8];
    lds_u32* dB1b = (lds_u32*)&Bs[1][(256 + t) * 8];

    auto stage0 = [&]() {   // into buffer 0
        __builtin_amdgcn_global_load_lds((g_u32*)pa0, dA0a, 16, 0, 0);
        if constexpr (BM == 128)
            __builtin_amdgcn_global_load_lds((g_u32*)pa1, dA0b, 16, 0, 0);
        __builtin_amdgcn_global_load_lds((g_u32*)pb0, dB0a, 16, 0, 0);
        __builtin_amdgcn_global_load_lds((g_u32*)pb1, dB0b, 16, 0, 0);
        pa0 += BK; pa1 += BK; pb0 += BK; pb1 += BK;
    };
    auto stage1 = [&]() {   // into buffer 1
        __builtin_amdgcn_global_load_lds((g_u32*)pa0, dA1a, 16, 0, 0);
        if constexpr (BM == 128)
            __builtin_amdgcn_global_load_lds((g_u32*)pa1, dA1b, 16, 0, 0);
        __builtin_amdgcn_global_load_lds((g_u32*)pb0, dB1a, 16, 0, 0);
        __builtin_amdgcn_global_load_lds((g_u32*)pb1, dB1b, 16, 0, 0);
        pa0 += BK; pa1 += BK; pb0 += BK; pb1 += BK;
    };

    // ---- compute: precomputed fragment byte-offsets ----
    const int swz = (g ^ ((ln >> 1) & 3)) << 4;
    int offA[FM], offB[4];
    #pragma unroll
    for (int fm = 0; fm < FM; ++fm)
        offA[fm] = (wr * (BM / 2) + fm * 16 + ln) * 64 + swz;
    #pragma unroll
    for (int fn = 0; fn < 4; ++fn)
        offB[fn] = (wc * 64 + fn * 16 + ln) * 64 + swz;

    f32x4 acc[FM][4];
    #pragma unroll
    for (int i = 0; i < FM; ++i)
        #pragma unroll
        for (int j = 0; j < 4; ++j) acc[i][j] = (f32x4){0.f, 0.f, 0.f, 0.f};

    auto compute = [&](const char* as, const char* bs) {
        bf16x8 af[FM], bfr[4];
        #pragma unroll
        for (int fm = 0; fm < FM; ++fm)
            af[fm] = *(const bf16x8*)(as + offA[fm]);
        #pragma unroll
        for (int fn = 0; fn < 4; ++fn)
            bfr[fn] = *(const bf16x8*)(bs + offB[fn]);
        #pragma unroll
        for (int fm = 0; fm < FM; ++fm)
            #pragma unroll
            for (int fn = 0; fn < 4; ++fn)
                acc[fm][fn] = __builtin_amdgcn_mfma_f32_16x16x32_bf16(
                    af[fm], bfr[fn], acc[fm][fn], 0, 0, 0);
    };

    stage0();                                   // tile 0
    for (int kt = 0; kt < NT; kt += 2) {
        __syncthreads();                        // buf0 staged; buf1 reads done
        stage1();                               // tile kt+1 (kt+1 <= 31 always)
        compute((const char*)As[0], (const char*)Bs[0]);
        __syncthreads();                        // buf1 staged; buf0 reads done
        if (kt + 2 < NT) stage0();              // tile kt+2
        compute((const char*)As[1], (const char*)Bs[1]);
    }

    const int rowbase = m0 + wr * (BM / 2);
    const int colbase = n0 + wc * 64;
    if (EPI == 1) {
        #pragma unroll
        for (int fm = 0; fm < FM; ++fm)
            #pragma unroll
            for (int fn = 0; fn < 4; ++fn)
                #pragma unroll
                for (int rr = 0; rr < 4; ++rr) {
                    const int row = rowbase + fm * 16 + g * 4 + rr;
                    oc[(size_t)row * N + colbase + fn * 16 + ln] = acc[fm][fn][rr];
                }
    } else {
        const int which = colbase >> 10;          // 0=q 1=k 2=v
        const int h = (colbase >> 6) & (NH - 1);
        if (which < 2) {
            // fused RoPE; q also scaled by log2e/8 (scores in log2 domain).
            unsigned short* dst = which == 0 ? oq : ok;
            const float scale = which == 0 ? 0.18033688011112042f : 1.f;
            const float cexp = -13.287712379549449f / 32.f;   // -log2(1e4)/32
            const float if0 = exp2f((float)ln * cexp);
            const float if1 = exp2f((float)(16 + ln) * cexp);
            #pragma unroll
            for (int fm = 0; fm < FM; ++fm)
                #pragma unroll
                for (int rr = 0; rr < 4; ++rr) {
                    const int row = rowbase + fm * 16 + g * 4 + rr;
                    const int b = row >> 11, s = row & (SEQ - 1);
                    float s0, c0, s1, c1;
                    __sincosf((float)s * if0, &s0, &c0);
                    __sincosf((float)s * if1, &s1, &c1);
                    const float x0 = acc[fm][0][rr], x1 = acc[fm][1][rr];
                    const float x2 = acc[fm][2][rr], x3 = acc[fm][3][rr];
                    const size_t base = (((size_t)b * NH + h) * SEQ + s) * DH;
                    dst[base + ln]      = f2bf((x0 * c0 - x2 * s0) * scale);
                    dst[base + 16 + ln] = f2bf((x1 * c1 - x3 * s1) * scale);
                    dst[base + 32 + ln] = f2bf((x2 * c0 + x0 * s0) * scale);
                    dst[base + 48 + ln] = f2bf((x3 * c1 + x1 * s1) * scale);
                }
        } else {
            #pragma unroll
            for (int fm = 0; fm < FM; ++fm)
                #pragma unroll
                for (int fn = 0; fn < 4; ++fn) {
                    const int row = rowbase + fm * 16 + g * 4;
                    const int b = row >> 11, s = row & (SEQ - 1);
                    const int d = fn * 16 + ln;
                    ushort4 pk;
                    pk.x = f2bf(acc[fm][fn][0]); pk.y = f2bf(acc[fm][fn][1]);
                    pk.z = f2bf(acc[fm][fn][2]); pk.w = f2bf(acc[fm][fn][3]);
                    *(ushort4*)&ovt[(((size_t)b * NH + h) * DH + d) * SEQ + s] = pk;
                }
        }
    }
}

// ---------------------------------------------------------------------------
// Flash attention, bf16 MFMA, causal, causal-fold paired (qtA=pi, qtB=31-pi).
// Round-14 structure (512-thread blocks, waves 0-3 tile A / 4-7 tile B,
// 16 waves/CU; in-register P via permuted K-row reads; static-max softmax;
// V-fragment hoist under softmax; XCD-grouped heads) with staging pointers
// strength-reduced (running pk/pv pointers, fixed LDS dests).
// ---------------------------------------------------------------------------
__global__ __launch_bounds__(512, 4)
void attn_mfma(const unsigned short* __restrict__ q,
               const unsigned short* __restrict__ k,
               const unsigned short* __restrict__ vt,
               unsigned short* __restrict__ ob)
{
    __shared__ unsigned short Ks[2][64 * 64];
    __shared__ unsigned short Vs[2][64 * 64];

    const int t  = threadIdx.x;
    const int l  = t & 63;
    const int w  = t >> 6;          // 0..7
    const int wq = w & 3;           // 16-row strip within the wave's tile
    const int g  = l >> 4;
    const int ln = l & 15;
    const int bid = blockIdx.x;     // 0..511
    const int xcd = bid & 7, jj = bid >> 3;
    const int bh = xcd * 4 + (jj >> 4);   // 4 heads per XCD -> L2-resident K/V
    const int pi = jj & 15;
    const int qtA = pi, qtB = 31 - pi;
    const int myqt = (w < 4) ? qtA : qtB;  // this wave's q-tile
    const size_t bqk = (size_t)bh * SEQ * DH;
    const size_t bv  = (size_t)bh * DH * SEQ;

    // Q fragments for this wave's 16 rows (q pre-scaled by log2e/8, RoPE'd)
    bf16x8 qf0, qf1;
    {
        const unsigned short* qp = q + bqk + (size_t)(myqt * 64 + wq * 16 + ln) * DH + g * 8;
        qf0 = *(const bf16x8*)qp;
        qf1 = *(const bf16x8*)(qp + 32);
    }

    f32x4 ao[4];
    #pragma unroll
    for (int i = 0; i < 4; ++i) ao[i] = (f32x4){0.f, 0.f, 0.f, 0.f};
    float l_ = 0.f;                 // per-lane partial denominator

    // staging: running global pointers, fixed LDS dests
    const int srow = t >> 3, ssl = t & 7;
    const int sg  = (srow & 3) | (((srow >> 3) & 1) << 2);
    const int slg = (ssl ^ sg) * 8;
    const unsigned short* pk = k  + bqk + (size_t)srow * DH + slg;       // tile 0
    const unsigned short* pv = vt + bv  + (size_t)srow * SEQ + slg;
    lds_u32* dK0 = (lds_u32*)&Ks[0][t * 8];
    lds_u32* dK1 = (lds_u32*)&Ks[1][t * 8];
    lds_u32* dV0 = (lds_u32*)&Vs[0][t * 8];
    lds_u32* dV1 = (lds_u32*)&Vs[1][t * 8];

    auto stagep = [&](int bufi) {
        lds_u32* dk = bufi ? dK1 : dK0;
        lds_u32* dv = bufi ? dV1 : dV0;
        __builtin_amdgcn_global_load_lds((g_u32*)pk, dk, 16, 0, 0);
        __builtin_amdgcn_global_load_lds((g_u32*)pv, dv, 16, 0, 0);
        pk += 64 * DH;
        pv += 64;
    };

    // lane-constant addressing pieces
    const int rowoffK = ((ln >> 2) * 8 + (ln & 3)) * 128;
    const int sK = (ln & 3) | (((ln >> 2) & 1) << 2);
    const int slotK0 = ((g ^ sK) << 4);
    const int slotK1 = (((g + 4) ^ sK) << 4);
    const int sV = (ln & 3) | (((ln >> 3) & 1) << 2);

    stagep(0);
    for (int kt = 0; kt <= qtB; ++kt) {
        __syncthreads();                      // buf[kt&1] staged & safe
        if (kt < qtB) stagep((kt + 1) & 1);
        const bool act = (kt <= myqt);
        const char* kb = (const char*)Ks[kt & 1];
        const char* vb = (const char*)Vs[kt & 1];

        if (act) {
            f32x4 s[4];
            #pragma unroll
            for (int nb = 0; nb < 4; ++nb) s[nb] = (f32x4){0.f, 0.f, 0.f, 0.f};

            __builtin_amdgcn_s_setprio(1);
            #pragma unroll
            for (int nb = 0; nb < 4; ++nb) {
                const char* kr = kb + ((nb >> 1) * 32 + (nb & 1) * 4) * 128 + rowoffK;
                bf16x8 kf0 = *(const bf16x8*)(kr + slotK0);
                bf16x8 kf1 = *(const bf16x8*)(kr + slotK1);
                s[nb] = __builtin_amdgcn_mfma_f32_16x16x32_bf16(kf0, qf0, s[nb], 0, 0, 0);
                s[nb] = __builtin_amdgcn_mfma_f32_16x16x32_bf16(kf1, qf1, s[nb], 0, 0, 0);
            }
            __builtin_amdgcn_s_setprio(0);

            // V-fragment reads issued now: in-order DS pipe retires them
            // underneath the softmax VALU; PV starts with no LDS stall.
            bf16x8 vf[8];
            #pragma unroll
            for (int ks = 0; ks < 2; ++ks)
                #pragma unroll
                for (int db = 0; db < 4; ++db) {
                    const int d = db * 16 + ln;
                    vf[ks * 4 + db] = *(const bf16x8*)(vb + d * 128 + (((ks * 4 + g) ^ sV) << 4));
                }

            // causal mask; score reg (nb,r) holds key=(nb>>1)*32+g*8+(nb&1)*4+r
            if (kt == myqt) {
                #pragma unroll
                for (int nb = 0; nb < 4; ++nb)
                    #pragma unroll
                    for (int r = 0; r < 4; ++r)
                        if ((nb >> 1) * 32 + g * 8 + (nb & 1) * 4 + r > wq * 16 + ln)
                            s[nb][r] = -INFINITY;
            }

            // static-max softmax -> PV A-fragments, in-register
            const float M2 = 28.853900817779268f;     // 20 * log2(e)
            bf16x8 pf[2];
            {
                float rs = 0.f;
                unsigned int dw[8];
                #pragma unroll
                for (int nb = 0; nb < 4; ++nb) {
                    float e[4];
                    #pragma unroll
                    for (int r = 0; r < 4; ++r)
                        e[r] = exp2_fast(s[nb][r] - M2);
                    rs += (e[0] + e[1]) + (e[2] + e[3]);
                    dw[nb * 2] = __builtin_amdgcn_perm(
                        __builtin_bit_cast(unsigned int, e[1]),
                        __builtin_bit_cast(unsigned int, e[0]), 0x07060302u);
                    dw[nb * 2 + 1] = __builtin_amdgcn_perm(
                        __builtin_bit_cast(unsigned int, e[3]),
                        __builtin_bit_cast(unsigned int, e[2]), 0x07060302u);
                }
                l_ += rs;
                pf[0] = __builtin_bit_cast(bf16x8, (u32x4){dw[0], dw[1], dw[2], dw[3]});
                pf[1] = __builtin_bit_cast(bf16x8, (u32x4){dw[4], dw[5], dw[6], dw[7]});
            }

            __builtin_amdgcn_s_setprio(1);
            #pragma unroll
            for (int ks = 0; ks < 2; ++ks)
                #pragma unroll
                for (int db = 0; db < 4; ++db)
                    ao[db] = __builtin_amdgcn_mfma_f32_16x16x32_bf16(
                        pf[ks], vf[ks * 4 + db], ao[db], 0, 0, 0);
            __builtin_amdgcn_s_setprio(0);
        }
    }

    // epilogue: reduce l across the 4 g-groups, normalize, store bf16
    l_ += __shfl_xor(l_, 16); l_ += __shfl_xor(l_, 32);
    const int b = bh >> 4, h = bh & (NH - 1);
    const float inv = 1.f / l_;
    #pragma unroll
    for (int r = 0; r < 4; ++r) {
        const float iv = __shfl(inv, g * 4 + r);
        const size_t row = (size_t)(b * SEQ + myqt * 64 + wq * 16 + g * 4 + r) * DMODEL + h * DH;
        #pragma unroll
        for (int db = 0; db < 4; ++db)
            ob[row + db * 16 + ln] = f2bf(ao[db][r] * iv);
    }
}

// ---------------------------------------------------------------------------
extern "C" void kernel_launch(void* const* d_in, const int* in_sizes, int n_in,
                              void* d_out, int out_size, void* d_ws, size_t ws_size,
                              hipStream_t stream)
{
    const float* x  = (const float*)d_in[0];
    const float* wq = (const float*)d_in[1];
    const float* wo = (const float*)d_in[2];
    float* out = (float*)d_out;

    const size_t NQ = (size_t)BATCH * NH * SEQ * DH;   // 4,194,304
    unsigned short* qb  = (unsigned short*)d_ws;
    unsigned short* kb  = qb + NQ;
    unsigned short* vtb = kb + NQ;
    unsigned short* ob  = vtb + NQ;
    unsigned short* xb  = ob + NQ;
    unsigned short* wqb = xb + NQ;
    unsigned short* wob = wqb + 3 * DMODEL * DMODEL;

    cast_all<<<4096, 256, 0, stream>>>(x, wq, wo, xb, wqb, wob);

    dim3 g1(3072 / 128, 4096 / 128);
    gemm_bf16<128, 0><<<g1, 256, 0, stream>>>(xb, wqb, nullptr, qb, kb, vtb, 4096, 3072);

    attn_mfma<<<512, 512, 0, stream>>>(qb, kb, vtb, ob);

    dim3 g3(1024 / 128, 4096 / 64);
    gemm_bf16<64, 1><<<g3, 256, 0, stream>>>(ob, wob, out, nullptr, nullptr, nullptr, 4096, 1024);
}

// Round 16
// 99.960 us; speedup vs baseline: 1.1203x; 1.1203x over previous
//
#include <hip/hip_runtime.h>
#include <hip/hip_bf16.h>
#include <cmath>

#define DMODEL 1024
#define NH 16
#define DH 64
#define SEQ 2048
#define BATCH 2

typedef __attribute__((ext_vector_type(8))) short bf16x8;
typedef __attribute__((ext_vector_type(4))) float f32x4;
typedef __attribute__((ext_vector_type(4))) unsigned int u32x4;
typedef __attribute__((ext_vector_type(8))) unsigned short u16x8;

typedef __attribute__((address_space(3))) unsigned int lds_u32;
typedef const __attribute__((address_space(1))) unsigned int g_u32;

__device__ __forceinline__ unsigned short f2bf(float f) {
    unsigned int u = __builtin_bit_cast(unsigned int, f);
    u += 0x7fffu + ((u >> 16) & 1u);
    return (unsigned short)(u >> 16);
}
// 2^x in one v_exp_f32
__device__ __forceinline__ float exp2_fast(float x) {
    float r;
    asm("v_exp_f32 %0, %1" : "=v"(r) : "v"(x));
    return r;
}

// ---------------------------------------------------------------------------
// fp32 -> bf16 cast of x, w_qkv, w_out in ONE kernel. 8 elems/thread.
// ---------------------------------------------------------------------------
__global__ __launch_bounds__(256)
void cast_all(const float* __restrict__ x, const float* __restrict__ wq,
              const float* __restrict__ wo, unsigned short* __restrict__ xb,
              unsigned short* __restrict__ wqb, unsigned short* __restrict__ wob)
{
    const int i = blockIdx.x * 256 + threadIdx.x;
    const float* src; unsigned short* dst; int off;
    if (i < 524288)      { src = x;  dst = xb;  off = i; }
    else if (i < 917504) { src = wq; dst = wqb; off = i - 524288; }
    else                 { src = wo; dst = wob; off = i - 917504; }
    const float4 a = *(const float4*)(src + (size_t)off * 8);
    const float4 b = *(const float4*)(src + (size_t)off * 8 + 4);
    u16x8 o;
    o[0] = f2bf(a.x); o[1] = f2bf(a.y); o[2] = f2bf(a.z); o[3] = f2bf(a.w);
    o[4] = f2bf(b.x); o[5] = f2bf(b.y); o[6] = f2bf(b.z); o[7] = f2bf(b.w);
    *(u16x8*)(dst + (size_t)off * 8) = o;
}

// ---------------------------------------------------------------------------
// QKV GEMM, 8-WAVE: C[4096,3072] = xb * wqb^T, K=1024, f32 accum.
// 512 threads = 8 waves (2 M-halves x 4 col-waves). Wave-tile: 64 rows x
// cols {cbase+ln, cbase+32+ln} with cbase=(wc>>1)*64+(wc&1)*16 -> each RoPE
// pair (d, d+32) stays in-wave. 24 waves/CU (3 blocks) hide staging latency.
// Staging: each thread 1 A- + 1 B- 16B global_load_lds, sigma-swizzled.
// Epilogue: fused RoPE (q scaled by log2e/8) -> q,k [B][H][S][64];
// v transposed -> vt [B][H][64][S].
// ---------------------------------------------------------------------------
__global__ __launch_bounds__(512, 6)
void gemm_qkv(const unsigned short* __restrict__ A,
              const unsigned short* __restrict__ B,
              unsigned short* __restrict__ oq, unsigned short* __restrict__ ok,
              unsigned short* __restrict__ ovt)
{
    constexpr int K = 1024;
    constexpr int BK = 32;
    constexpr int NT = K / BK;           // 32
    __shared__ unsigned short As[2][128 * BK];
    __shared__ unsigned short Bs[2][128 * BK];

    const int t  = threadIdx.x;
    const int l  = t & 63;
    const int w  = t >> 6;               // 0..7
    const int g  = l >> 4;
    const int ln = l & 15;
    const int wr = w >> 2;               // 0..1  M-half
    const int wc = w & 3;                // 0..3  col-wave
    const int m0 = blockIdx.y * 128;
    const int n0 = blockIdx.x * 128;
    const int cbase = (wc >> 1) * 64 + (wc & 1) * 16;

    auto stage = [&](int kt, int bufi) {
        const int r = t >> 2, slot = t & 3;
        const int kk = kt * BK + ((slot ^ ((r >> 1) & 3)) * 8);
        const unsigned short* ga = A + (size_t)(m0 + r) * K + kk;
        const unsigned short* gb = B + (size_t)(n0 + r) * K + kk;
        __builtin_amdgcn_global_load_lds((g_u32*)ga,
            (lds_u32*)&As[bufi][t * 8], 16, 0, 0);
        __builtin_amdgcn_global_load_lds((g_u32*)gb,
            (lds_u32*)&Bs[bufi][t * 8], 16, 0, 0);
    };

    f32x4 acc[4][2];
    #pragma unroll
    for (int i = 0; i < 4; ++i)
        #pragma unroll
        for (int j = 0; j < 2; ++j) acc[i][j] = (f32x4){0.f, 0.f, 0.f, 0.f};

    const int swz = (g ^ ((ln >> 1) & 3)) << 4;

    stage(0, 0);
    for (int kt = 0; kt < NT; ++kt) {
        __syncthreads();
        if (kt + 1 < NT) stage(kt + 1, (kt + 1) & 1);
        const char* as = (const char*)As[kt & 1];
        const char* bs = (const char*)Bs[kt & 1];
        bf16x8 af[4], bfr[2];
        #pragma unroll
        for (int fm = 0; fm < 4; ++fm)
            af[fm] = *(const bf16x8*)(as + (wr * 64 + fm * 16 + ln) * 64 + swz);
        #pragma unroll
        for (int fn = 0; fn < 2; ++fn)
            bfr[fn] = *(const bf16x8*)(bs + (cbase + fn * 32 + ln) * 64 + swz);
        #pragma unroll
        for (int fm = 0; fm < 4; ++fm)
            #pragma unroll
            for (int fn = 0; fn < 2; ++fn)
                acc[fm][fn] = __builtin_amdgcn_mfma_f32_16x16x32_bf16(
                    af[fm], bfr[fn], acc[fm][fn], 0, 0, 0);
    }

    const int rowbase = m0 + wr * 64;
    const int chead = n0 + (wc >> 1) * 64;    // 64-aligned -> one head
    const int which = chead >> 10;            // 0=q 1=k 2=v
    const int h = (chead >> 6) & (NH - 1);
    if (which < 2) {
        // fused RoPE; q also scaled by log2e/8 (scores in log2 domain).
        unsigned short* dst = which == 0 ? oq : ok;
        const float scale = which == 0 ? 0.18033688011112042f : 1.f;
        const float cexp = -13.287712379549449f / 32.f;   // -log2(1e4)/32
        const int d0 = (wc & 1) * 16 + ln;                // 0..31
        const float iff = exp2f((float)d0 * cexp);
        #pragma unroll
        for (int fm = 0; fm < 4; ++fm)
            #pragma unroll
            for (int rr = 0; rr < 4; ++rr) {
                const int row = rowbase + fm * 16 + g * 4 + rr;
                const int b = row >> 11, s = row & (SEQ - 1);
                float sn, cs;
                __sincosf((float)s * iff, &sn, &cs);
                const float x0 = acc[fm][0][rr], x1 = acc[fm][1][rr];
                const size_t base = (((size_t)b * NH + h) * SEQ + s) * DH;
                dst[base + d0]      = f2bf((x0 * cs - x1 * sn) * scale);
                dst[base + 32 + d0] = f2bf((x1 * cs + x0 * sn) * scale);
            }
    } else {
        #pragma unroll
        for (int fm = 0; fm < 4; ++fm)
            #pragma unroll
            for (int fn = 0; fn < 2; ++fn) {
                const int row = rowbase + fm * 16 + g * 4;   // 4 consecutive s
                const int b = row >> 11, s = row & (SEQ - 1);
                const int d = (wc & 1) * 16 + fn * 32 + ln;
                ushort4 pk;
                pk.x = f2bf(acc[fm][fn][0]); pk.y = f2bf(acc[fm][fn][1]);
                pk.z = f2bf(acc[fm][fn][2]); pk.w = f2bf(acc[fm][fn][3]);
                *(ushort4*)&ovt[(((size_t)b * NH + h) * DH + d) * SEQ + s] = pk;
            }
    }
}

// ---------------------------------------------------------------------------
// Out-projection GEMM (round-14 form): C[4096,1024] = ob * wob^T, fp32 out.
// BM=64 tile, 256 threads = 4 waves (2x2).
// ---------------------------------------------------------------------------
__global__ __launch_bounds__(256)
void gemm_out(const unsigned short* __restrict__ A,
              const unsigned short* __restrict__ B,
              float* __restrict__ oc, int M, int N)
{
    constexpr int K = 1024;
    constexpr int BK = 32;
    constexpr int NT = K / BK;
    constexpr int BM = 64;
    constexpr int FM = 2;
    __shared__ unsigned short As[2][BM * BK];
    __shared__ unsigned short Bs[2][128 * BK];

    const int t  = threadIdx.x;
    const int l  = t & 63;
    const int w  = t >> 6;
    const int g  = l >> 4;
    const int ln = l & 15;
    const int wr = w >> 1, wc = w & 1;
    const int m0 = blockIdx.y * BM;
    const int n0 = blockIdx.x * 128;

    auto stage = [&](int kt, int bufi) {
        {
            const int r = t >> 2, slot = t & 3;
            const int kk = kt * BK + ((slot ^ ((r >> 1) & 3)) * 8);
            const unsigned short* ga = A + (size_t)(m0 + r) * K + kk;
            __builtin_amdgcn_global_load_lds((g_u32*)ga,
                (lds_u32*)&As[bufi][t * 8], 16, 0, 0);
        }
        #pragma unroll
        for (int i = 0; i < 2; ++i) {
            const int n = i * 256 + t;
            const int r = n >> 2, slot = n & 3;
            const int kk = kt * BK + ((slot ^ ((r >> 1) & 3)) * 8);
            const unsigned short* gb = B + (size_t)(n0 + r) * K + kk;
            __builtin_amdgcn_global_load_lds((g_u32*)gb,
                (lds_u32*)&Bs[bufi][n * 8], 16, 0, 0);
        }
    };

    f32x4 acc[FM][4];
    #pragma unroll
    for (int i = 0; i < FM; ++i)
        #pragma unroll
        for (int j = 0; j < 4; ++j) acc[i][j] = (f32x4){0.f, 0.f, 0.f, 0.f};

    const int swz = (g ^ ((ln >> 1) & 3)) << 4;

    stage(0, 0);
    for (int kt = 0; kt < NT; ++kt) {
        __syncthreads();
        if (kt + 1 < NT) stage(kt + 1, (kt + 1) & 1);
        const char* as = (const char*)As[kt & 1];
        const char* bs = (const char*)Bs[kt & 1];
        bf16x8 af[FM], bfr[4];
        #pragma unroll
        for (int fm = 0; fm < FM; ++fm)
            af[fm] = *(const bf16x8*)(as + (wr * (BM / 2) + fm * 16 + ln) * 64 + swz);
        #pragma unroll
        for (int fn = 0; fn < 4; ++fn)
            bfr[fn] = *(const bf16x8*)(bs + (wc * 64 + fn * 16 + ln) * 64 + swz);
        #pragma unroll
        for (int fm = 0; fm < FM; ++fm)
            #pragma unroll
            for (int fn = 0; fn < 4; ++fn)
                acc[fm][fn] = __builtin_amdgcn_mfma_f32_16x16x32_bf16(
                    af[fm], bfr[fn], acc[fm][fn], 0, 0, 0);
    }

    const int rowbase = m0 + wr * (BM / 2);
    const int colbase = n0 + wc * 64;
    #pragma unroll
    for (int fm = 0; fm < FM; ++fm)
        #pragma unroll
        for (int fn = 0; fn < 4; ++fn)
            #pragma unroll
            for (int rr = 0; rr < 4; ++rr) {
                const int row = rowbase + fm * 16 + g * 4 + rr;
                oc[(size_t)row * N + colbase + fn * 16 + ln] = acc[fm][fn][rr];
            }
}

// ---------------------------------------------------------------------------
// Flash attention (round-14 form, verbatim): bf16 MFMA, causal, causal-fold
// paired (qtA=pi, qtB=31-pi). 512-thread blocks, waves 0-3 tile A / 4-7 B,
// 16 waves/CU; in-register P via permuted K-row reads; static-max softmax;
// V-fragment hoist under softmax; XCD-grouped heads (K/V L2-resident).
// ---------------------------------------------------------------------------
__global__ __launch_bounds__(512, 4)
void attn_mfma(const unsigned short* __restrict__ q,
               const unsigned short* __restrict__ k,
               const unsigned short* __restrict__ vt,
               unsigned short* __restrict__ ob)
{
    __shared__ unsigned short Ks[2][64 * 64];
    __shared__ unsigned short Vs[2][64 * 64];

    const int t  = threadIdx.x;
    const int l  = t & 63;
    const int w  = t >> 6;          // 0..7
    const int wq = w & 3;           // 16-row strip within the wave's tile
    const int g  = l >> 4;
    const int ln = l & 15;
    const int bid = blockIdx.x;     // 0..511
    const int xcd = bid & 7, jj = bid >> 3;
    const int bh = xcd * 4 + (jj >> 4);   // 4 heads per XCD -> L2-resident K/V
    const int pi = jj & 15;
    const int qtA = pi, qtB = 31 - pi;
    const int myqt = (w < 4) ? qtA : qtB;  // this wave's q-tile
    const size_t bqk = (size_t)bh * SEQ * DH;
    const size_t bv  = (size_t)bh * DH * SEQ;

    // Q fragments for this wave's 16 rows (q pre-scaled by log2e/8, RoPE'd)
    bf16x8 qf0, qf1;
    {
        const unsigned short* qp = q + bqk + (size_t)(myqt * 64 + wq * 16 + ln) * DH + g * 8;
        qf0 = *(const bf16x8*)qp;
        qf1 = *(const bf16x8*)(qp + 32);
    }

    f32x4 ao[4];
    #pragma unroll
    for (int i = 0; i < 4; ++i) ao[i] = (f32x4){0.f, 0.f, 0.f, 0.f};
    float l_ = 0.f;                 // per-lane partial denominator

    // stage with source pre-swizzle: LDS[row][sl] = G[row][sl ^ sigma(row)];
    // 512 threads -> one K 16B-DMA + one V 16B-DMA per thread.
    auto stage = [&](int kt, int bufi) {
        const int row = t >> 3, sl = t & 7;
        const int sg  = (row & 3) | (((row >> 3) & 1) << 2);
        const int slg = (sl ^ sg) * 8;
        const unsigned short* gk = k  + bqk + (size_t)(kt * 64 + row) * DH + slg;
        const unsigned short* gv = vt + bv  + (size_t)row * SEQ + kt * 64 + slg;
        __builtin_amdgcn_global_load_lds((g_u32*)gk,
            (lds_u32*)&Ks[bufi][t * 8], 16, 0, 0);
        __builtin_amdgcn_global_load_lds((g_u32*)gv,
            (lds_u32*)&Vs[bufi][t * 8], 16, 0, 0);
    };

    // lane-constant addressing pieces
    const int rowoffK = ((ln >> 2) * 8 + (ln & 3)) * 128;
    const int sK = (ln & 3) | (((ln >> 2) & 1) << 2);
    const int slotK0 = ((g ^ sK) << 4);
    const int slotK1 = (((g + 4) ^ sK) << 4);
    const int sV = (ln & 3) | (((ln >> 3) & 1) << 2);

    stage(0, 0);
    for (int kt = 0; kt <= qtB; ++kt) {
        __syncthreads();                      // buf[kt&1] staged & safe
        if (kt < qtB) stage(kt + 1, (kt + 1) & 1);
        const bool act = (kt <= myqt);
        const char* kb = (const char*)Ks[kt & 1];
        const char* vb = (const char*)Vs[kt & 1];

        if (act) {
            f32x4 s[4];
            #pragma unroll
            for (int nb = 0; nb < 4; ++nb) s[nb] = (f32x4){0.f, 0.f, 0.f, 0.f};

            __builtin_amdgcn_s_setprio(1);
            #pragma unroll
            for (int nb = 0; nb < 4; ++nb) {
                const char* kr = kb + ((nb >> 1) * 32 + (nb & 1) * 4) * 128 + rowoffK;
                bf16x8 kf0 = *(const bf16x8*)(kr + slotK0);
                bf16x8 kf1 = *(const bf16x8*)(kr + slotK1);
                s[nb] = __builtin_amdgcn_mfma_f32_16x16x32_bf16(kf0, qf0, s[nb], 0, 0, 0);
                s[nb] = __builtin_amdgcn_mfma_f32_16x16x32_bf16(kf1, qf1, s[nb], 0, 0, 0);
            }
            __builtin_amdgcn_s_setprio(0);

            // issue V-fragment reads NOW: the in-order DS pipe retires them
            // underneath the softmax VALU below; PV needs no LDS reads.
            bf16x8 vf[8];
            #pragma unroll
            for (int ks = 0; ks < 2; ++ks)
                #pragma unroll
                for (int db = 0; db < 4; ++db) {
                    const int d = db * 16 + ln;
                    vf[ks * 4 + db] = *(const bf16x8*)(vb + d * 128 + (((ks * 4 + g) ^ sV) << 4));
                }

            // causal mask; score reg (nb,r) holds key=(nb>>1)*32+g*8+(nb&1)*4+r
            if (kt == myqt) {
                #pragma unroll
                for (int nb = 0; nb < 4; ++nb)
                    #pragma unroll
                    for (int r = 0; r < 4; ++r)
                        if ((nb >> 1) * 32 + g * 8 + (nb & 1) * 4 + r > wq * 16 + ln)
                            s[nb][r] = -INFINITY;
            }

            // static-max softmax -> PV A-fragments, in-register
            const float M2 = 28.853900817779268f;     // 20 * log2(e)
            bf16x8 pf[2];
            {
                float rs = 0.f;
                unsigned int dw[8];
                #pragma unroll
                for (int nb = 0; nb < 4; ++nb) {
                    float e[4];
                    #pragma unroll
                    for (int r = 0; r < 4; ++r)
                        e[r] = exp2_fast(s[nb][r] - M2);
                    rs += (e[0] + e[1]) + (e[2] + e[3]);
                    dw[nb * 2] = __builtin_amdgcn_perm(
                        __builtin_bit_cast(unsigned int, e[1]),
                        __builtin_bit_cast(unsigned int, e[0]), 0x07060302u);
                    dw[nb * 2 + 1] = __builtin_amdgcn_perm(
                        __builtin_bit_cast(unsigned int, e[3]),
                        __builtin_bit_cast(unsigned int, e[2]), 0x07060302u);
                }
                l_ += rs;
                pf[0] = __builtin_bit_cast(bf16x8, (u32x4){dw[0], dw[1], dw[2], dw[3]});
                pf[1] = __builtin_bit_cast(bf16x8, (u32x4){dw[4], dw[5], dw[6], dw[7]});
            }

            __builtin_amdgcn_s_setprio(1);
            #pragma unroll
            for (int ks = 0; ks < 2; ++ks)
                #pragma unroll
                for (int db = 0; db < 4; ++db)
                    ao[db] = __builtin_amdgcn_mfma_f32_16x16x32_bf16(
                        pf[ks], vf[ks * 4 + db], ao[db], 0, 0, 0);
            __builtin_amdgcn_s_setprio(0);
        }
    }

    // epilogue: reduce l across the 4 g-groups, normalize, store bf16
    l_ += __shfl_xor(l_, 16); l_ += __shfl_xor(l_, 32);
    const int b = bh >> 4, h = bh & (NH - 1);
    const float inv = 1.f / l_;
    #pragma unroll
    for (int r = 0; r < 4; ++r) {
        const float iv = __shfl(inv, g * 4 + r);
        const size_t row = (size_t)(b * SEQ + myqt * 64 + wq * 16 + g * 4 + r) * DMODEL + h * DH;
        #pragma unroll
        for (int db = 0; db < 4; ++db)
            ob[row + db * 16 + ln] = f2bf(ao[db][r] * iv);
    }
}

// ---------------------------------------------------------------------------
extern "C" void kernel_launch(void* const* d_in, const int* in_sizes, int n_in,
                              void* d_out, int out_size, void* d_ws, size_t ws_size,
                              hipStream_t stream)
{
    const float* x  = (const float*)d_in[0];
    const float* wq = (const float*)d_in[1];
    const float* wo = (const float*)d_in[2];
    float* out = (float*)d_out;

    const size_t NQ = (size_t)BATCH * NH * SEQ * DH;   // 4,194,304
    unsigned short* qb  = (unsigned short*)d_ws;
    unsigned short* kb  = qb + NQ;
    unsigned short* vtb = kb + NQ;
    unsigned short* ob  = vtb + NQ;
    unsigned short* xb  = ob + NQ;
    unsigned short* wqb = xb + NQ;
    unsigned short* wob = wqb + 3 * DMODEL * DMODEL;

    cast_all<<<4096, 256, 0, stream>>>(x, wq, wo, xb, wqb, wob);

    dim3 g1(3072 / 128, 4096 / 128);
    gemm_qkv<<<g1, 512, 0, stream>>>(xb, wqb, qb, kb, vtb);

    attn_mfma<<<512, 512, 0, stream>>>(qb, kb, vtb, ob);

    dim3 g3(1024 / 128, 4096 / 64);
    gemm_out<<<g3, 256, 0, stream>>>(ob, wob, out, 4096, 1024);
}